// Round 13
// baseline (308.104 us; speedup 1.0000x reference)
//
#include <hip/hip_runtime.h>
#include <hip/hip_bf16.h>

// ---------------------------------------------------------------------------
// ResidualSAGEBlock: block-private bucket sort (block-major cells) ->
// fused [LDS csr-build + gather-mean] -> MFMA bf16 dual GEMM (+replicated
// BN stats) -> finalize(BN+res+ReLU).  N=100000, D=128, E=1600000.
// R2:  CSR gather replaced float-atomic scatter: 3095->812us.
// R4:  multi-block scan: 761->546us.
// R5:  MFMA bf16 GEMM: 546->493us.
// R6 FAILED: global-atomic bucket append (cross-XCD line sharing): ->757us.
// R7:  3-pass block-private counting sort: 757->409us.
// R8:  bf16 gather source; packed pairs: 409->306us.
// R9 FAILED: cooperative grid.sync tail ~370us at 1563 blocks: ->310us.
// R10: bf16 h round-trip: 306->303us.
// R11: 12->9 dispatches: ->296us (mfma atomic contention 64us found).
// R12: 32-way replicated stats fixed mfma: 296->288us.
// R13: ~10us/dispatch overhead dominates -> 9->7 dispatches: prep folded into
//      bhist; csrbuild+gather fused (64-node buckets, sort in LDS, no global
//      csr/offs); pairs cells block-major => bscatter writes one contiguous
//      private region (zero cross-block line sharing).
// ---------------------------------------------------------------------------

#define D128 128
#define BSH  6          // log2(nodes per bucket)
#define BSZ  64         // nodes per bucket
#define MAXBUK 2048     // LDS bound for buckets (NBUK=1563 actual)
#define SBLK 256        // sort blocks
#define CAP  2048       // csrgather LDS capacity (mean 1024, +32 sigma)
#define SREP 32         // stat replicas

typedef short bf16x8 __attribute__((ext_vector_type(8)));
typedef float f32x4  __attribute__((ext_vector_type(4)));

static __device__ __forceinline__ unsigned short f2bf(float f) {
    unsigned u = __builtin_bit_cast(unsigned, f);
    unsigned r = u + 0x7fffu + ((u >> 16) & 1u);   // round-to-nearest-even
    return (unsigned short)(r >> 16);
}
static __device__ __forceinline__ float bflo(unsigned u) {   // low bf16 -> f32
    return __builtin_bit_cast(float, u << 16);
}
static __device__ __forceinline__ float bfhi(unsigned u) {   // high bf16 -> f32
    return __builtin_bit_cast(float, u & 0xffff0000u);
}

// --- sort pass 1: per-block bucket histogram + x->bf16 + prep (Bsw, stats) -
// ghist is BLOCK-major: ghist[b*NBUK + i] (contiguous per block, coalesced).
__global__ __launch_bounds__(256) void bhist_kernel(
    const int* __restrict__ dst, int* __restrict__ ghist,
    const float* __restrict__ x, unsigned short* __restrict__ xb,
    const float* __restrict__ Wl, const float* __restrict__ Wr,
    unsigned short* __restrict__ Bsw, float* __restrict__ stats,
    int E, int chunk, int NBUK, int total4) {
    __shared__ int lh[MAXBUK];
    int tid = threadIdx.x;
    int b   = blockIdx.x;
    // folded prep: zero replicated stats (blocks 0..31), build Bsw (0..15)
    if (b < SREP) stats[b * 256 + tid] = 0.f;
    if (b < 16) {
        int idx = b * 256 + tid;       // 0..4095
        int l = idx & 63;
        int c = (idx >> 6) & 7;
        int t = idx >> 9;
        int d = c * 16 + (l & 15);
        int kbase = t * 32 + (l >> 4) * 8;
        unsigned short o[8];
#pragma unroll
        for (int j = 0; j < 8; ++j) {
            int k = kbase + j;
            float v = (k < 128) ? Wl[d * 128 + k] : Wr[d * 128 + (k - 128)];
            o[j] = f2bf(v);
        }
        *(uint4*)(Bsw + (size_t)idx * 8) = *(const uint4*)o;
    }
    for (int i = tid; i < NBUK; i += 256) lh[i] = 0;
    __syncthreads();
    int beg = b * chunk;
    int end = min(beg + chunk, E);
    for (int i = beg + tid; i < end; i += 256)
        atomicAdd(&lh[dst[i] >> BSH], 1);
    __syncthreads();
    for (int i = tid; i < NBUK; i += 256) ghist[(size_t)b * NBUK + i] = lh[i];
    // streaming conversion x (fp32) -> xb (bf16)
    for (int i = b * 256 + tid; i < total4; i += 256 * SBLK) {
        float4 v = ((const float4*)x)[i];
        uint2 o;
        o.x = (unsigned)f2bf(v.x) | ((unsigned)f2bf(v.y) << 16);
        o.y = (unsigned)f2bf(v.z) | ((unsigned)f2bf(v.w) << 16);
        ((uint2*)xb)[i] = o;
    }
}

// --- scan stage 1: per-block (1024 elems) partial sums over ghist ----------
__global__ __launch_bounds__(256) void partial_kernel(const int* __restrict__ deg,
                                                      int* __restrict__ bsum, int N) {
    int tid  = threadIdx.x;
    int base = blockIdx.x * 1024 + tid * 4;
    int s = 0;
    if (base + 3 < N) {
        int4 v = *(const int4*)(deg + base);
        s = v.x + v.y + v.z + v.w;
    } else {
        for (int i = base; i < N; ++i) s += deg[i];
    }
    __shared__ int red[256];
    red[tid] = s;
    __syncthreads();
    for (int off = 128; off > 0; off >>= 1) {
        if (tid < off) red[tid] += red[tid + off];
        __syncthreads();
    }
    if (tid == 0) bsum[blockIdx.x] = red[0];
}

// --- scan stage 2: per-chunk scan; ebsum via in-block scan of <=512 bsums --
__global__ __launch_bounds__(256) void scan_final_kernel(
    const int* __restrict__ deg, const int* __restrict__ bsum,
    int* __restrict__ gsc, int M, int NB2, int E) {
    __shared__ int sb[2][256];
    int tid = threadIdx.x;
    // pairs trick: sp[t] = bsum[2t]+bsum[2t+1], scan 256 wide covers 512 chunks
    int b0 = (2 * tid     < NB2) ? bsum[2 * tid]     : 0;
    int b1 = (2 * tid + 1 < NB2) ? bsum[2 * tid + 1] : 0;
    sb[0][tid] = b0 + b1;
    __syncthreads();
    int pi = 0;
    for (int off = 1; off < 256; off <<= 1) {
        int u = sb[pi][tid];
        if (tid >= off) u += sb[pi][tid - off];
        sb[pi ^ 1][tid] = u;
        __syncthreads();
        pi ^= 1;
    }
    int c = blockIdx.x;
    int ebsum = ((c >> 1) > 0 ? sb[pi][(c >> 1) - 1] : 0)
              + ((c & 1) ? bsum[c - 1] : 0);
    __syncthreads();

    int base = c * 1024 + tid * 4;
    int d0 = 0, d1 = 0, d2 = 0, d3 = 0;
    if (base + 3 < M) {
        int4 v = *(const int4*)(deg + base);
        d0 = v.x; d1 = v.y; d2 = v.z; d3 = v.w;
    } else {
        if (base     < M) d0 = deg[base];
        if (base + 1 < M) d1 = deg[base + 1];
        if (base + 2 < M) d2 = deg[base + 2];
        if (base + 3 < M) d3 = deg[base + 3];
    }
    int s = d0 + d1 + d2 + d3;
    sb[0][tid] = s;
    __syncthreads();
    pi = 0;
    for (int off = 1; off < 256; off <<= 1) {
        int u = sb[pi][tid];
        if (tid >= off) u += sb[pi][tid - off];
        sb[pi ^ 1][tid] = u;
        __syncthreads();
        pi ^= 1;
    }
    int pre = sb[pi][tid] - s + ebsum;
    if (base + 3 < M) {
        int4 o = make_int4(pre, pre + d0, pre + d0 + d1, pre + d0 + d1 + d2);
        *(int4*)(gsc + base) = o;
    } else {
        int p = pre;
        if (base     < M) { gsc[base]     = p; p += d0; }
        if (base + 1 < M) { gsc[base + 1] = p; p += d1; }
        if (base + 2 < M) { gsc[base + 2] = p; p += d2; }
        if (base + 3 < M) { gsc[base + 3] = p; }
    }
    if (c == 0 && tid == 0) gsc[M] = E;
}

// --- sort pass 2: scatter packed (src<<6 | nib) into block-private region --
// Block b's cells gsc[b*NBUK .. (b+1)*NBUK) form ONE contiguous pairs range:
// every 64B line written by exactly this block.
__global__ __launch_bounds__(256) void bscatter_kernel(
    const int* __restrict__ src, const int* __restrict__ dst,
    const int* __restrict__ gsc, unsigned* __restrict__ pairs,
    int E, int chunk, int NBUK) {
    __shared__ int lcur[MAXBUK];
    int tid = threadIdx.x;
    int b   = blockIdx.x;
    for (int i = tid; i < NBUK; i += 256)
        lcur[i] = gsc[(size_t)b * NBUK + i];
    __syncthreads();
    int beg = b * chunk;
    int end = min(beg + chunk, E);
    for (int i = beg + tid; i < end; i += 256) {
        int d = dst[i];
        int s = src[i];
        int pos = atomicAdd(&lcur[d >> BSH], 1);
        pairs[pos] = ((unsigned)s << BSH) | (unsigned)(d & (BSZ - 1));
    }
}

// --- fused CSR-build + gather-mean (one block per 64-node bucket) ----------
// Stage bucket's pairs (256 cells, block-major) into LDS, counting-sort into
// lcsr, then gather xb rows via LDS edge lists -> aggb. No global csr/offs.
__global__ __launch_bounds__(256) void csrgather_kernel(
    const unsigned* __restrict__ pairs, const int* __restrict__ gsc,
    const unsigned short* __restrict__ xb, unsigned short* __restrict__ aggb,
    int N, int NBUK) {
    __shared__ int praw[CAP];
    __shared__ int lcsr[CAP];
    __shared__ int lstart[BSZ + 1];
    __shared__ int lcur[BSZ];
    __shared__ int sbuf[2][256];
    int i   = blockIdx.x;
    int tid = threadIdx.x;
    int nlo = i << BSH;
    // cell (tid, i): start + length
    size_t idx = (size_t)tid * NBUK + i;
    int st   = gsc[idx];
    int lenc = gsc[idx + 1] - st;
    sbuf[0][tid] = lenc;
    __syncthreads();
    int pi = 0;
    for (int off = 1; off < 256; off <<= 1) {
        int u = sbuf[pi][tid];
        if (tid >= off) u += sbuf[pi][tid - off];
        sbuf[pi ^ 1][tid] = u;
        __syncthreads();
        pi ^= 1;
    }
    int cellbase = sbuf[pi][tid] - lenc;
    int total    = sbuf[pi][255];

    int l = tid & 31, half = l >> 4, fl = l & 15;

    if (total <= CAP) {
        for (int j = 0; j < lenc; ++j) praw[cellbase + j] = (int)pairs[st + j];
        if (tid < BSZ) lcur[tid] = 0;
        __syncthreads();
        for (int k = tid; k < total; k += 256)
            atomicAdd(&lcur[praw[k] & (BSZ - 1)], 1);
        __syncthreads();
        int cv = (tid < BSZ) ? lcur[tid] : 0;
        sbuf[0][tid] = cv;
        __syncthreads();
        pi = 0;
        for (int off = 1; off < 256; off <<= 1) {
            int u = sbuf[pi][tid];
            if (tid >= off) u += sbuf[pi][tid - off];
            sbuf[pi ^ 1][tid] = u;
            __syncthreads();
            pi ^= 1;
        }
        if (tid < BSZ) {
            int pre = sbuf[pi][tid] - cv;
            lstart[tid] = pre;
            lcur[tid]   = pre;
        }
        if (tid == 0) lstart[BSZ] = total;
        __syncthreads();
        for (int k = tid; k < total; k += 256) {
            int p = praw[k];
            int pos = atomicAdd(&lcur[p & (BSZ - 1)], 1);
            lcsr[pos] = p >> BSH;
        }
        __syncthreads();
        // gather rounds: 8 nodes per round (32 lanes/node), 8 rounds
        for (int rr = 0; rr < 8; ++rr) {
            int nib = rr * 8 + (tid >> 5);
            int n   = nlo + nib;
            int beg = lstart[nib], end = lstart[nib + 1];
            int deg = end - beg;
            float f[8] = {0.f, 0.f, 0.f, 0.f, 0.f, 0.f, 0.f, 0.f};
            float g[8] = {0.f, 0.f, 0.f, 0.f, 0.f, 0.f, 0.f, 0.f};
            int k = beg;
            for (; k + 8 <= end; k += 8) {
                int s0 = lcsr[k + half];
                int s1 = lcsr[k + 2 + half];
                int s2 = lcsr[k + 4 + half];
                int s3 = lcsr[k + 6 + half];
                uint4 v0 = *(const uint4*)(xb + (size_t)s0 * D128 + fl * 8);
                uint4 v1 = *(const uint4*)(xb + (size_t)s1 * D128 + fl * 8);
                uint4 v2 = *(const uint4*)(xb + (size_t)s2 * D128 + fl * 8);
                uint4 v3 = *(const uint4*)(xb + (size_t)s3 * D128 + fl * 8);
                f[0] += bflo(v0.x); f[1] += bfhi(v0.x);
                f[2] += bflo(v0.y); f[3] += bfhi(v0.y);
                f[4] += bflo(v0.z); f[5] += bfhi(v0.z);
                f[6] += bflo(v0.w); f[7] += bfhi(v0.w);
                g[0] += bflo(v1.x); g[1] += bfhi(v1.x);
                g[2] += bflo(v1.y); g[3] += bfhi(v1.y);
                g[4] += bflo(v1.z); g[5] += bfhi(v1.z);
                g[6] += bflo(v1.w); g[7] += bfhi(v1.w);
                f[0] += bflo(v2.x); f[1] += bfhi(v2.x);
                f[2] += bflo(v2.y); f[3] += bfhi(v2.y);
                f[4] += bflo(v2.z); f[5] += bfhi(v2.z);
                f[6] += bflo(v2.w); f[7] += bfhi(v2.w);
                g[0] += bflo(v3.x); g[1] += bfhi(v3.x);
                g[2] += bflo(v3.y); g[3] += bfhi(v3.y);
                g[4] += bflo(v3.z); g[5] += bfhi(v3.z);
                g[6] += bflo(v3.w); g[7] += bfhi(v3.w);
            }
            if (end - k >= 4) {
                int s0 = lcsr[k + half];
                int s1 = lcsr[k + 2 + half];
                uint4 v0 = *(const uint4*)(xb + (size_t)s0 * D128 + fl * 8);
                uint4 v1 = *(const uint4*)(xb + (size_t)s1 * D128 + fl * 8);
                f[0] += bflo(v0.x); f[1] += bfhi(v0.x);
                f[2] += bflo(v0.y); f[3] += bfhi(v0.y);
                f[4] += bflo(v0.z); f[5] += bfhi(v0.z);
                f[6] += bflo(v0.w); f[7] += bfhi(v0.w);
                g[0] += bflo(v1.x); g[1] += bfhi(v1.x);
                g[2] += bflo(v1.y); g[3] += bfhi(v1.y);
                g[4] += bflo(v1.z); g[5] += bfhi(v1.z);
                g[6] += bflo(v1.w); g[7] += bfhi(v1.w);
                k += 4;
            }
            if (end - k >= 2) {
                int s0 = lcsr[k + half];
                uint4 v0 = *(const uint4*)(xb + (size_t)s0 * D128 + fl * 8);
                f[0] += bflo(v0.x); f[1] += bfhi(v0.x);
                f[2] += bflo(v0.y); f[3] += bfhi(v0.y);
                f[4] += bflo(v0.z); f[5] += bfhi(v0.z);
                f[6] += bflo(v0.w); f[7] += bfhi(v0.w);
                k += 2;
            }
            if (k < end && half == 0) {
                int s0 = lcsr[k];
                uint4 v0 = *(const uint4*)(xb + (size_t)s0 * D128 + fl * 8);
                f[0] += bflo(v0.x); f[1] += bfhi(v0.x);
                f[2] += bflo(v0.y); f[3] += bfhi(v0.y);
                f[4] += bflo(v0.z); f[5] += bfhi(v0.z);
                f[6] += bflo(v0.w); f[7] += bfhi(v0.w);
            }
            float inv = (deg > 0) ? 1.0f / (float)deg : 0.f;
#pragma unroll
            for (int j = 0; j < 8; ++j) {
                f[j] += g[j];
                f[j] += __shfl_xor(f[j], 16, 64);
            }
            if (half == 0) {
                uint4 o;
                o.x = (unsigned)f2bf(f[0] * inv) | ((unsigned)f2bf(f[1] * inv) << 16);
                o.y = (unsigned)f2bf(f[2] * inv) | ((unsigned)f2bf(f[3] * inv) << 16);
                o.z = (unsigned)f2bf(f[4] * inv) | ((unsigned)f2bf(f[5] * inv) << 16);
                o.w = (unsigned)f2bf(f[6] * inv) | ((unsigned)f2bf(f[7] * inv) << 16);
                *(uint4*)(aggb + (size_t)n * D128 + fl * 8) = o;
            }
        }
    } else {
        // overflow fallback (statistically unreachable): direct global scan
        for (int rr = 0; rr < 8; ++rr) {
            int nib = rr * 8 + (tid >> 5);
            int n   = nlo + nib;
            if (half != 0) continue;
            float f[8] = {0.f, 0.f, 0.f, 0.f, 0.f, 0.f, 0.f, 0.f};
            int deg = 0;
            for (int c = 0; c < SBLK; ++c) {
                size_t id2 = (size_t)c * NBUK + i;
                int s2 = gsc[id2], e2 = gsc[id2 + 1];
                for (int k = s2; k < e2; ++k) {
                    unsigned p = pairs[k];
                    if ((int)(p & (BSZ - 1u)) == nib) {
                        int s = (int)(p >> BSH);
                        uint4 v0 = *(const uint4*)(xb + (size_t)s * D128 + fl * 8);
                        f[0] += bflo(v0.x); f[1] += bfhi(v0.x);
                        f[2] += bflo(v0.y); f[3] += bfhi(v0.y);
                        f[4] += bflo(v0.z); f[5] += bfhi(v0.z);
                        f[6] += bflo(v0.w); f[7] += bfhi(v0.w);
                        ++deg;
                    }
                }
            }
            float inv = (deg > 0) ? 1.0f / (float)deg : 0.f;
            uint4 o;
            o.x = (unsigned)f2bf(f[0] * inv) | ((unsigned)f2bf(f[1] * inv) << 16);
            o.y = (unsigned)f2bf(f[2] * inv) | ((unsigned)f2bf(f[3] * inv) << 16);
            o.z = (unsigned)f2bf(f[4] * inv) | ((unsigned)f2bf(f[5] * inv) << 16);
            o.w = (unsigned)f2bf(f[6] * inv) | ((unsigned)f2bf(f[7] * inv) << 16);
            *(uint4*)(aggb + (size_t)n * D128 + fl * 8) = o;
        }
    }
}

// --- MFMA dual GEMM -> bf16 h + BN stats into replicated accumulators ------
// K=256: ksteps 0-3 read aggb, 4-7 read xb. No b_l (cancelled by BN).
__global__ __launch_bounds__(256) void mfma_kernel(
    const unsigned short* __restrict__ aggb, const unsigned short* __restrict__ xb,
    const unsigned short* __restrict__ Bsw,
    unsigned short* __restrict__ h16, float* __restrict__ stats, int N) {
    __shared__ float red[4][256];
    int tid  = threadIdx.x;
    int w    = tid >> 6;
    int lane = tid & 63;
    int lc   = lane & 15;    // tile col
    int lq   = lane >> 4;    // quarter
    int rowBase = blockIdx.x * 128 + w * 32;

    f32x4 acc[2][8];
#pragma unroll
    for (int c = 0; c < 8; ++c) {
        f32x4 z = {0.f, 0.f, 0.f, 0.f};
        acc[0][c] = z;
        acc[1][c] = z;
    }
    int r0  = rowBase + lc;
    int r1  = rowBase + 16 + lc;
    int r0c = min(r0, N - 1);
    int r1c = min(r1, N - 1);
    for (int t = 0; t < 8; ++t) {
        const unsigned short* p0;
        const unsigned short* p1;
        if (t < 4) {
            int off = t * 32 + lq * 8;
            p0 = aggb + (size_t)r0 * D128 + off;
            p1 = aggb + (size_t)r1 * D128 + off;
        } else {
            int off = (t - 4) * 32 + lq * 8;
            p0 = xb + (size_t)r0c * D128 + off;
            p1 = xb + (size_t)r1c * D128 + off;
        }
        bf16x8 a0 = *(const bf16x8*)p0;
        bf16x8 a1 = *(const bf16x8*)p1;
#pragma unroll
        for (int c = 0; c < 8; ++c) {
            bf16x8 bf = *(const bf16x8*)(Bsw + ((size_t)((t * 8 + c) * 64 + lane)) * 8);
            acc[0][c] = __builtin_amdgcn_mfma_f32_16x16x32_bf16(a0, bf, acc[0][c], 0, 0, 0);
            acc[1][c] = __builtin_amdgcn_mfma_f32_16x16x32_bf16(a1, bf, acc[1][c], 0, 0, 0);
        }
    }
    float s[8], ss[8];
#pragma unroll
    for (int c = 0; c < 8; ++c) { s[c] = 0.f; ss[c] = 0.f; }
#pragma unroll
    for (int rh = 0; rh < 2; ++rh) {
#pragma unroll
        for (int reg = 0; reg < 4; ++reg) {
            int row = rowBase + rh * 16 + lq * 4 + reg;   // C-layout row
            if (row < N) {
#pragma unroll
                for (int c = 0; c < 8; ++c) {
                    float v = acc[rh][c][reg];
                    h16[(size_t)row * D128 + c * 16 + lc] = f2bf(v);
                    s[c]  += v;
                    ss[c] += v * v;
                }
            }
        }
    }
#pragma unroll
    for (int c = 0; c < 8; ++c) {
        s[c]  += __shfl_xor(s[c], 16, 64);
        s[c]  += __shfl_xor(s[c], 32, 64);
        ss[c] += __shfl_xor(ss[c], 16, 64);
        ss[c] += __shfl_xor(ss[c], 32, 64);
    }
    if (lq == 0) {
#pragma unroll
        for (int c = 0; c < 8; ++c) {
            red[w][c * 16 + lc]       = s[c];
            red[w][128 + c * 16 + lc] = ss[c];
        }
    }
    __syncthreads();
    float tot = red[0][tid] + red[1][tid] + red[2][tid] + red[3][tid];
    atomicAdd(&stats[(blockIdx.x & (SREP - 1)) * 256 + tid], tot);
}

// --- finalize: sum stat replicas, BN params in LDS, out = relu(...) --------
__global__ __launch_bounds__(256) void finalize_kernel(
    const unsigned short* __restrict__ h16, const unsigned short* __restrict__ xb,
    const float* __restrict__ stats, const float* __restrict__ gamma,
    const float* __restrict__ beta, float* __restrict__ out,
    long long total4, float invN) {
    __shared__ float sscl[D128];
    __shared__ float sshf[D128];
    int tid = threadIdx.x;
    if (tid < D128) {
        float sum = 0.f, sq = 0.f;
#pragma unroll
        for (int r = 0; r < SREP; ++r) {
            sum += stats[r * 256 + tid];
            sq  += stats[r * 256 + 128 + tid];
        }
        float mean = sum * invN;
        float var  = sq * invN - mean * mean;
        float istd = rsqrtf(var + 1e-5f);
        float sc   = gamma[tid] * istd;
        sscl[tid] = sc;
        sshf[tid] = beta[tid] - mean * sc;
    }
    __syncthreads();
    long long i = (long long)blockIdx.x * 256 + tid;
    if (i >= total4) return;
    int d = (int)((i * 4) & 127);
    uint2 hv = ((const uint2*)h16)[i];
    uint2 xv = ((const uint2*)xb)[i];
    float4 o;
    o.x = fmaxf(fmaf(bflo(hv.x), sscl[d],     sshf[d])     + bflo(xv.x), 0.f);
    o.y = fmaxf(fmaf(bfhi(hv.x), sscl[d + 1], sshf[d + 1]) + bfhi(xv.x), 0.f);
    o.z = fmaxf(fmaf(bflo(hv.y), sscl[d + 2], sshf[d + 2]) + bflo(xv.y), 0.f);
    o.w = fmaxf(fmaf(bfhi(hv.y), sscl[d + 3], sshf[d + 3]) + bfhi(xv.y), 0.f);
    ((float4*)out)[i] = o;
}

extern "C" void kernel_launch(void* const* d_in, const int* in_sizes, int n_in,
                              void* d_out, int out_size, void* d_ws, size_t ws_size,
                              hipStream_t stream) {
    const float* x     = (const float*)d_in[0];
    const int*   eidx  = (const int*)d_in[1];
    const float* W_l   = (const float*)d_in[2];
    const float* W_r   = (const float*)d_in[4];
    const float* gamma = (const float*)d_in[5];
    const float* beta  = (const float*)d_in[6];

    const int D = in_sizes[3];            // 128
    const int N = in_sizes[0] / D;        // 100000
    const int E = in_sizes[1] / 2;        // 1600000

    const int* src = eidx;
    const int* dst = eidx + E;

    const int NBLK  = (N + 127) / 128;        // mfma blocks (782)
    const int Npad  = NBLK * 128;             // padded rows (100096)
    const int NBUK  = (N + BSZ - 1) / BSZ;    // buckets (1563)
    const int M     = NBUK * SBLK;            // cells (400128)
    const int NB2   = (M + 1023) / 1024;      // scan chunks (391, <=512)
    const int chunk = (E + SBLK - 1) / SBLK;  // edges per sort block (6250)
    const int total4 = N * D128 / 4;          // float4s in x

    // workspace layout (byte cursor, 64B-aligned chunks)
    char* wp = (char*)d_ws;
    auto alloc = [&](size_t bytes) {
        char* p = wp;
        wp += (bytes + 63) & ~(size_t)63;
        return p;
    };
    float*    stats = (float*)   alloc((size_t)SREP * 256 * 4);
    unsigned* pairs = (unsigned*)alloc((size_t)E * 4);
    int*      ghist = (int*)     alloc((size_t)M * 4);
    int*      gsc   = (int*)     alloc((size_t)(M + 1) * 4);
    int*      bsum  = (int*)     alloc(1024 * 4);
    unsigned short* Bsw  = (unsigned short*)alloc(4096 * 16);
    unsigned short* xb   = (unsigned short*)alloc((size_t)N * D128 * 2);
    unsigned short* aggb = (unsigned short*)alloc((size_t)Npad * D128 * 2);
    unsigned short* h16  = (unsigned short*)alloc((size_t)N * D128 * 2);

    float* outp = (float*)d_out;
    float invN = 1.0f / (float)N;

    // 1. bucket hist + x->bf16 + Bsw/stats prep
    bhist_kernel<<<SBLK, 256, 0, stream>>>(dst, ghist, x, xb, W_l, W_r,
                                           Bsw, stats, E, chunk, NBUK, total4);
    // 2-3. scan of cell histogram (block-major)
    partial_kernel<<<NB2, 256, 0, stream>>>(ghist, bsum, M);
    scan_final_kernel<<<NB2, 256, 0, stream>>>(ghist, bsum, gsc, M, NB2, E);
    // 4. scatter into block-private contiguous regions
    bscatter_kernel<<<SBLK, 256, 0, stream>>>(src, dst, gsc, pairs, E, chunk, NBUK);
    // 5. fused LDS csr-build + gather-mean
    csrgather_kernel<<<NBUK, 256, 0, stream>>>(pairs, gsc, xb, aggb, N, NBUK);
    // 6. MFMA dual GEMM + stats
    mfma_kernel<<<NBLK, 256, 0, stream>>>(aggb, xb, Bsw, h16, stats, N);
    // 7. BN + residual + ReLU
    {
        long long t4 = (long long)N * D128 / 4;
        finalize_kernel<<<(int)((t4 + 255) / 256), 256, 0, stream>>>(
            h16, xb, stats, gamma, beta, outp, t4, invN);
    }
}